// Round 3
// baseline (493.636 us; speedup 1.0000x reference)
//
#include <hip/hip_runtime.h>

// OverlapWindowMHA2d on MI355X (gfx950) — R2.
// prep (w->bf16) ; merged fused qkv+MFMA-attention (both branches, barrier-free K-loop,
// direct-global weight fragments) ; head GEMM (swapped operands -> float4 stores).
// Workspace (~101.3 MB): o_cat bf16 [b][win 1024][n 16][c 384] ; w1b ; w2b ; whb

typedef unsigned short u16;
using bf16x8 = __attribute__((ext_vector_type(8))) short;
using f32x4  = __attribute__((ext_vector_type(4))) float;
using u16x8  = __attribute__((ext_vector_type(8))) unsigned short;
using u16x4  = __attribute__((ext_vector_type(4))) unsigned short;

#define CIN 192

__device__ __forceinline__ u16 f2bf(float f) {
    unsigned int x; __builtin_memcpy(&x, &f, 4);
    return (u16)((x + 0x7FFFu + ((x >> 16) & 1u)) >> 16);
}
// x-tile LDS swizzle: scalar [tok][c] writes spread over banks, 16B k-blocks contiguous.
__device__ __forceinline__ int xcol(int c, int tok) {
    int blk = (c >> 3) ^ ((tok ^ (tok >> 4)) & 7);
    return blk * 8 + (c & 7);
}

__global__ void prep_conv(const float* __restrict__ w1, const float* __restrict__ w2,
                          const float* __restrict__ wh,
                          u16* __restrict__ w1b, u16* __restrict__ w2b, u16* __restrict__ whb) {
    int i = blockIdx.x * 256 + threadIdx.x;            // 294912 total
    if (i < 110592)        w1b[i] = f2bf(w1[i]);
    else if (i < 221184)   w2b[i - 110592] = f2bf(w2[i - 110592]);
    else                   whb[i - 221184] = f2bf(wh[i - 221184]);
}

// ---------------------------------------------------------------------------
// Merged fused QKV (MFMA, M=576 N=64 K=192) + MFMA attention. 4 windows/block.
// blocks [0,2048): branch1 ; [2048,4424): branch2 (padded, crop-remapped store).
// 3 barriers total. Weight A-frags direct from global (L2-hot).
// ---------------------------------------------------------------------------
__global__ __launch_bounds__(256, 2) void qkv_attn(const float* __restrict__ x,
                                                   const u16* __restrict__ w1b,
                                                   const u16* __restrict__ w2b,
                                                   const float* __restrict__ bias1,
                                                   const float* __restrict__ bias2,
                                                   u16* __restrict__ ocat) {
    // phase1: xl [0,25600) = [64 tok][200] u16
    // phase2: qk [0,50176) = [64 tok][392] u16 (Q 0..191 scaled, K 192..383)
    //         vt [50176,74752) = [4 win][6 head][32 d][16 m] u16
    __shared__ __align__(16) char smem[74752];
    u16* xl = (u16*)smem;
    u16* qk = (u16*)smem;
    u16* vt = (u16*)(smem + 50176);

    const int tid  = threadIdx.x;
    const int wave = tid >> 6, lane = tid & 63;
    const int lo16 = lane & 15, quad = lane >> 4;

    int bi = blockIdx.x, BR, b, wy, g;
    if (bi < 2048) {
        BR = 0; b = bi >> 8; int rem = bi & 255; wy = rem >> 3; g = rem & 7;
    } else {
        bi -= 2048; BR = 1; b = bi / 297; int rem = bi % 297; wy = rem / 9; g = rem % 9;
    }
    const u16*  wb   = BR ? w2b : w1b;
    const float* bias = BR ? bias2 : bias1;
    const int hbase = wy * 4, wbase = g * 16;

    // --- x tile: 4 windows x 16 tok x 192 ch -> LDS bf16 (64B-coalesced) ---
#pragma unroll
    for (int it = 0; it < 12; ++it) {
        int i = it * 256 + tid;          // c(192) x y(4) x xc(4)
        int c = i >> 4, y = (i >> 2) & 3, xc = i & 3;
        float e0, e1, e2, e3;
        if (BR == 0) {
            const float4 v = *reinterpret_cast<const float4*>(
                &x[(((size_t)b * CIN + c) * 128 + hbase + y) * 128 + wbase + xc * 4]);
            e0 = v.x; e1 = v.y; e2 = v.z; e3 = v.w;
        } else {
            int h = hbase + y - 2;
            int w0 = wbase + xc * 4 - 2;
            bool hok = (unsigned)h < 128u;
            const float* row = &x[(((size_t)b * CIN + c) * 128 + h) * 128];
            if (hok && w0 >= 0 && w0 + 3 < 128) {
                float2 p0 = *reinterpret_cast<const float2*>(&row[w0]);
                float2 p1 = *reinterpret_cast<const float2*>(&row[w0 + 2]);
                e0 = p0.x; e1 = p0.y; e2 = p1.x; e3 = p1.y;
            } else {
                e0 = (hok && w0 >= 0 && w0 < 128)     ? row[w0]     : 0.f;
                e1 = (hok && w0+1 >= 0 && w0+1 < 128) ? row[w0 + 1] : 0.f;
                e2 = (hok && w0+2 >= 0 && w0+2 < 128) ? row[w0 + 2] : 0.f;
                e3 = (hok && w0+3 >= 0 && w0+3 < 128) ? row[w0 + 3] : 0.f;
            }
        }
        int t0 = xc * 16 + y * 4;
        xl[(t0 + 0) * 200 + xcol(c, t0 + 0)] = f2bf(e0);
        xl[(t0 + 1) * 200 + xcol(c, t0 + 1)] = f2bf(e1);
        xl[(t0 + 2) * 200 + xcol(c, t0 + 2)] = f2bf(e2);
        xl[(t0 + 3) * 200 + xcol(c, t0 + 3)] = f2bf(e3);
    }
    __syncthreads();

    // --- barrier-free K-loop: qkv[co 576][tok 64], A-frags direct from global ---
    f32x4 acc[9][4];
#pragma unroll
    for (int mt = 0; mt < 9; ++mt)
#pragma unroll
        for (int nt = 0; nt < 4; ++nt) acc[mt][nt] = f32x4{0.f, 0.f, 0.f, 0.f};

#pragma unroll
    for (int s = 0; s < 6; ++s) {
        bf16x8 bfr[4];
#pragma unroll
        for (int nt = 0; nt < 4; ++nt) {
            int tok = nt * 16 + lo16;
            int kb = s * 4 + quad;
            bfr[nt] = *reinterpret_cast<const bf16x8*>(
                &xl[tok * 200 + ((kb ^ ((tok ^ (tok >> 4)) & 7)) << 3)]);
        }
#pragma unroll
        for (int mt = 0; mt < 9; ++mt) {
            bf16x8 afr = *reinterpret_cast<const bf16x8*>(
                &wb[(size_t)(wave * 144 + mt * 16 + lo16) * 192 + s * 32 + quad * 8]);
#pragma unroll
            for (int nt = 0; nt < 4; ++nt)
                acc[mt][nt] = __builtin_amdgcn_mfma_f32_16x16x32_bf16(afr, bfr[nt], acc[mt][nt], 0, 0, 0);
        }
    }
    __syncthreads();

    // --- restage: Q(scaled)+K -> qk ; V -> vt (transposed). acc dies here. ---
    const float scale = 0.17677669529663687f;     // 1/sqrt(32)
#pragma unroll
    for (int mt = 0; mt < 9; ++mt) {
        int co0 = wave * 144 + mt * 16 + quad * 4;
        const float4 bv = *reinterpret_cast<const float4*>(&bias[co0]);
#pragma unroll
        for (int nt = 0; nt < 4; ++nt) {
            int tok = nt * 16 + lo16;
            float v0 = acc[mt][nt][0] + bv.x, v1 = acc[mt][nt][1] + bv.y;
            float v2 = acc[mt][nt][2] + bv.z, v3 = acc[mt][nt][3] + bv.w;
            if (co0 < 192) { v0 *= scale; v1 *= scale; v2 *= scale; v3 *= scale; }
            if (co0 < 384) {
                u16x4 pk = {f2bf(v0), f2bf(v1), f2bf(v2), f2bf(v3)};
                *reinterpret_cast<u16x4*>(&qk[tok * 392 + co0]) = pk;
            } else {
                int dh = co0 - 384;
                int head = dh >> 5, d0 = dh & 31;
                int win = tok >> 4, m = tok & 15;
                u16* vrow = &vt[((win * 6 + head) * 32 + d0) * 16 + m];
                vrow[0]  = f2bf(v0);
                vrow[16] = f2bf(v1);
                vrow[32] = f2bf(v2);
                vrow[48] = f2bf(v3);
            }
        }
    }
    __syncthreads();

    // --- attention: wave = window; S^T MFMA, softmax, shfl-transpose P, PV MFMA ---
    {
        const int win = wave;
        const u16* qbase = qk + (size_t)(win * 16) * 392;
        const bf16x8 z8 = {};
        const f32x4 zc = {0.f, 0.f, 0.f, 0.f};
        const int sl0 = (quad & 1) * 32 + lo16;       // shfl source (valid for quad<2)

        bool dov; size_t dst = 0;
        if (BR == 0) {
            int wg = wy * 32 + g * 4 + win;
            dst = (((size_t)(b * 1024 + wg)) * 16 + lo16) * 384;
            dov = true;
        } else {
            int wx = g * 4 + win;
            int h = wy * 4 + (lo16 >> 2) - 2;
            int w = wx * 4 + (lo16 & 3) - 2;
            dov = (wx < 33) && (unsigned)h < 128u && (unsigned)w < 128u;
            if (dov) {
                int wg = (h >> 2) * 32 + (w >> 2);
                int nn = (h & 3) * 4 + (w & 3);
                dst = (((size_t)(b * 1024 + wg)) * 16 + nn) * 384 + 192;
            }
        }
#pragma unroll
        for (int head = 0; head < 6; ++head) {
            bf16x8 kfr = *reinterpret_cast<const bf16x8*>(
                &qbase[lo16 * 392 + 192 + head * 32 + quad * 8]);
            bf16x8 qfr = *reinterpret_cast<const bf16x8*>(
                &qbase[lo16 * 392 + head * 32 + quad * 8]);
            f32x4 st = __builtin_amdgcn_mfma_f32_16x16x32_bf16(kfr, qfr, zc, 0, 0, 0);
            // softmax over key index m (4 regs x quads), column n = lo16
            float mx = fmaxf(fmaxf(st[0], st[1]), fmaxf(st[2], st[3]));
            mx = fmaxf(mx, __shfl_xor(mx, 16));
            mx = fmaxf(mx, __shfl_xor(mx, 32));
            float p0 = __expf(st[0] - mx), p1 = __expf(st[1] - mx);
            float p2 = __expf(st[2] - mx), p3 = __expf(st[3] - mx);
            float sum = p0 + p1 + p2 + p3;
            sum += __shfl_xor(sum, 16);
            sum += __shfl_xor(sum, 32);
            float inv = 1.0f / sum;
            // transpose P via shuffles: pf[j] = P[n=lo16][m=quad*8+j]
            float f0 = __shfl(p0, sl0),      f1 = __shfl(p1, sl0);
            float f2 = __shfl(p2, sl0),      f3 = __shfl(p3, sl0);
            float f4 = __shfl(p0, sl0 + 16), f5 = __shfl(p1, sl0 + 16);
            float f6 = __shfl(p2, sl0 + 16), f7 = __shfl(p3, sl0 + 16);
            u16x8 pk = {f2bf(f0), f2bf(f1), f2bf(f2), f2bf(f3),
                        f2bf(f4), f2bf(f5), f2bf(f6), f2bf(f7)};
            bf16x8 pf = (quad < 2) ? *reinterpret_cast<bf16x8*>(&pk) : z8;
            const u16* vbase = &vt[(win * 6 + head) * 512];
#pragma unroll
            for (int half = 0; half < 2; ++half) {
                bf16x8 av = (quad < 2)
                    ? *reinterpret_cast<const bf16x8*>(&vbase[(half * 16 + lo16) * 16 + quad * 8]) : z8;
                f32x4 o = __builtin_amdgcn_mfma_f32_16x16x32_bf16(av, pf, zc, 0, 0, 0);
                if (dov) {
                    u16x4 ok = {f2bf(o[0] * inv), f2bf(o[1] * inv),
                                f2bf(o[2] * inv), f2bf(o[3] * inv)};
                    *reinterpret_cast<u16x4*>(&ocat[dst + head * 32 + half * 16 + quad * 4]) = ok;
                }
            }
        }
    }
}

// ---------------------------------------------------------------------------
// head GEMM, swapped operands: D[token][co] so a lane's 4 acc regs = 4 consecutive
// w pixels -> float4 stores. A = o_cat tokens (LDS-staged), B = w_head rows (global, L2).
// ---------------------------------------------------------------------------
__global__ __launch_bounds__(256, 3) void head_gemm(const u16* __restrict__ ocat,
                                                    const u16* __restrict__ whb,
                                                    const float* __restrict__ bh,
                                                    float* __restrict__ out) {
    __shared__ __align__(16) u16 bt[64 * 392];
    const int tid = threadIdx.x;
    const int wave = tid >> 6, lane = tid & 63;
    const int lo16 = lane & 15, quad = lane >> 4;

    int bi = blockIdx.x;                    // 8 * 32 * 8 = 2048
    int b = bi >> 8; int rem = bi & 255;
    int wy = rem >> 3, g = rem & 7;
    const size_t gbase = ((size_t)(b * 1024 + wy * 32 + g * 4) * 16) * 384;

#pragma unroll
    for (int it = 0; it < 12; ++it) {       // 48KB contiguous, u16x8 coalesced
        int i = it * 256 + tid;
        u16x8 v = *reinterpret_cast<const u16x8*>(&ocat[gbase + (size_t)i * 8]);
        int row = i / 48, kc = i - row * 48;
        *reinterpret_cast<u16x8*>(&bt[row * 392 + kc * 8]) = v;
    }
    __syncthreads();

    f32x4 acc[4][3];
#pragma unroll
    for (int mt = 0; mt < 4; ++mt)
#pragma unroll
        for (int nt = 0; nt < 3; ++nt) acc[mt][nt] = f32x4{0.f, 0.f, 0.f, 0.f};

#pragma unroll
    for (int s = 0; s < 12; ++s) {
        int k0 = s * 32;
        bf16x8 a[4], bb[3];
#pragma unroll
        for (int mt = 0; mt < 4; ++mt)      // A: token rows from LDS
            a[mt] = *reinterpret_cast<const bf16x8*>(&bt[(mt * 16 + lo16) * 392 + k0 + quad * 8]);
#pragma unroll
        for (int nt = 0; nt < 3; ++nt)      // B: w_head rows from global (L2-hot)
            bb[nt] = *reinterpret_cast<const bf16x8*>(
                &whb[(size_t)((wave * 3 + nt) * 16 + lo16) * 384 + k0 + quad * 8]);
#pragma unroll
        for (int mt = 0; mt < 4; ++mt)
#pragma unroll
            for (int nt = 0; nt < 3; ++nt)
                acc[mt][nt] = __builtin_amdgcn_mfma_f32_16x16x32_bf16(a[mt], bb[nt], acc[mt][nt], 0, 0, 0);
    }

    // epilogue: lane col = co, rows = 4 consecutive w pixels -> float4 store
    const int h = wy * 4 + quad;
#pragma unroll
    for (int nt = 0; nt < 3; ++nt) {
        int co = (wave * 3 + nt) * 16 + lo16;
        float bias = bh[co];
#pragma unroll
        for (int mt = 0; mt < 4; ++mt) {
            float4 v = {acc[mt][nt][0] + bias, acc[mt][nt][1] + bias,
                        acc[mt][nt][2] + bias, acc[mt][nt][3] + bias};
            *reinterpret_cast<float4*>(
                &out[(((size_t)b * CIN + co) * 128 + h) * 128 + (g * 4 + mt) * 4]) = v;
        }
    }
}

// ---------------------------------------------------------------------------
extern "C" void kernel_launch(void* const* d_in, const int* in_sizes, int n_in,
                              void* d_out, int out_size, void* d_ws, size_t ws_size,
                              hipStream_t stream) {
    const float* x  = (const float*)d_in[0];
    const float* w1 = (const float*)d_in[1];
    const float* b1 = (const float*)d_in[2];
    const float* w2 = (const float*)d_in[3];
    const float* b2 = (const float*)d_in[4];
    const float* wh = (const float*)d_in[5];
    const float* bh = (const float*)d_in[6];
    float* out = (float*)d_out;

    char* ws = (char*)d_ws;
    u16* ocat = (u16*)ws;
    u16* w1b  = (u16*)(ws + 100663296);
    u16* w2b  = (u16*)(ws + 100884480);
    u16* whb  = (u16*)(ws + 101105664);

    prep_conv<<<1152, 256, 0, stream>>>(w1, w2, wh, w1b, w2b, whb);
    qkv_attn<<<4424, 256, 0, stream>>>(x, w1b, w2b, b1, b2, ocat);
    head_gemm<<<2048, 256, 0, stream>>>(ocat, whb, bh, out);
}